// Round 9
// baseline (4157.167 us; speedup 1.0000x reference)
//
#include <hip/hip_runtime.h>

typedef _Float16 f16;
typedef _Float16 f16x4 __attribute__((ext_vector_type(4)));
typedef _Float16 f16x8 __attribute__((ext_vector_type(8)));
typedef float    f32x4 __attribute__((ext_vector_type(4)));

#define MFMA(a,b,c) __builtin_amdgcn_mfma_f32_16x16x32_f16(a,b,c,0,0,0)
#define SBAR() __builtin_amdgcn_sched_barrier(0)
#define BARRIER() do { SBAR(); __builtin_amdgcn_s_barrier(); SBAR(); } while (0)
#define VMCNT(n) do { SBAR(); asm volatile("s_waitcnt vmcnt(" #n ")" ::: "memory"); SBAR(); } while (0)
#define LGKM0() do { asm volatile("s_waitcnt lgkmcnt(0)" ::: "memory"); SBAR(); } while (0)

__device__ __forceinline__ void gload_lds16(const f16* g, f16* l) {
  __builtin_amdgcn_global_load_lds(
      (const __attribute__((address_space(1))) unsigned int*)g,
      (__attribute__((address_space(3))) unsigned int*)l, 16, 0, 0);
}

// ---------------------------------------------------------------------------
// f32 -> f16 elementwise convert (weights only)
// ---------------------------------------------------------------------------
__global__ __launch_bounds__(256)
void tof16_kernel(const float* __restrict__ x, f16* __restrict__ y, int n4) {
  int i = blockIdx.x * 256 + threadIdx.x;
  if (i >= n4) return;
  f32x4 v = ((const f32x4*)x)[i];
  f16x4 h;
#pragma unroll
  for (int j = 0; j < 4; j++) h[j] = (f16)v[j];
  ((f16x4*)y)[i] = h;
}

// ---------------------------------------------------------------------------
// Fused convert + transpose: in f32 [z][2048][1024]
//   -> rm f16 [z][2048][1024] (row-major)  and  tr f16 [z][1024][2048]
// ---------------------------------------------------------------------------
__global__ __launch_bounds__(256)
void prep_f16_kernel(const float* __restrict__ in, f16* __restrict__ rm,
                     f16* __restrict__ tr) {
  __shared__ f16 t[64][68];
  const int tid = threadIdx.x;
  const size_t z = blockIdx.z;
  const int n0 = blockIdx.x * 64, h0 = blockIdx.y * 64;
  const int rr = tid >> 4, cc = (tid & 15) * 4;
#pragma unroll
  for (int p = 0; p < 4; p++) {
    int n = rr + p * 16;
    f32x4 v = *(const f32x4*)(in + ((size_t)z * 2048 + n0 + n) * 1024 + h0 + cc);
    f16x4 h;
#pragma unroll
    for (int j = 0; j < 4; j++) h[j] = (f16)v[j];
    *(f16x4*)&t[n][cc] = h;
    *(f16x4*)(rm + ((size_t)z * 2048 + n0 + n) * 1024 + h0 + cc) = h;
  }
  __syncthreads();
#pragma unroll
  for (int p = 0; p < 4; p++) {
    int h = rr + p * 16;
    f16x4 o;
#pragma unroll
    for (int j = 0; j < 4; j++) o[j] = t[cc + j][h];
    *(f16x4*)(tr + ((size_t)z * 1024 + h0 + h) * 2048 + n0 + cc) = o;
  }
}

// ---------------------------------------------------------------------------
// 256x256-tile GEMM, 64 KB LDS -> 2 blocks/CU:
//   C = A(f16,[M][K],lda) * B(f16,[N][K],ldb)^T
// BK=32 per step, one buffer pair (A,B: 16 KB each) double-buffered across
// steps. Per step: {12 ds_read | issue 4 gloads (t+1) | lgkmcnt(0) |
// setprio + 32 MFMA | vmcnt(0) | barrier} -- ONE barrier per K-step; the
// vmcnt(0) drain sits a full MFMA cluster after issue so load latency hides
// under compute, and the co-resident second block fills residual stalls.
// Block mapping (batch-per-XCD): u = id % ZB (round-robins XCDs),
//   k = id / ZB; bx = k % gx (fast), by = k / gx.
// ---------------------------------------------------------------------------
template <int OUTF32>
__global__ __launch_bounds__(512, 4)
void gemm256(const f16* __restrict__ Ag, size_t zA,
             const f16* __restrict__ Bg, size_t zB,
             void* __restrict__ Cg, size_t zC,
             int lda, int ldb, int ldc, int K, int ZB, int gx) {
  __shared__ f16 sm[4][8192];  // [c*2 + mat][256*32], 64 KB
  const int tid = threadIdx.x;
  const int id = blockIdx.x;
  const size_t z = id % ZB;
  const int k = id / ZB;
  const int bx = k % gx, by = k / gx;
  const f16* A = Ag + z * zA + (size_t)bx * 256 * lda;
  const f16* B = Bg + z * zB + (size_t)by * 256 * ldb;

  const int lane = tid & 63, w = tid >> 6;
  const int wm = w >> 2, wn = w & 3;
  const int lr = lane & 15, kg = lane >> 4;
  const int sx = (kg ^ ((lr >> 1) & 3)) << 3;      // swizzled chunk for reads
  const int aoff = wm * 4096 + lr * 32 + sx;
  const int boff = wn * 2048 + lr * 32 + sx;
  const int colx = (((tid & 3) ^ ((tid >> 3) & 3)) << 3);  // pre-swizzled src col
  const int srow = tid >> 2;
  const int wls = w * 512;  // wave-uniform LDS base (halfs) per issue

  f32x4 acc[8][4] = {};
  f16x8 af[8], bf[4];

#define STAGE(cc, mat, ktc) do {                                               \
    const f16* gs = ((mat) ? B : A) + (size_t)srow * ((mat) ? ldb : lda) +     \
                    (ktc) + colx;                                              \
    f16* ls = &sm[(cc) * 2 + (mat)][wls];                                      \
    gload_lds16(gs, ls);                                                       \
    gload_lds16(gs + (size_t)128 * ((mat) ? ldb : lda), ls + 4096);            \
  } while (0)

#define LOADS(cc) do { _Pragma("unroll")                                       \
    for (int fm = 0; fm < 8; fm++)                                             \
      af[fm] = *(const f16x8*)&sm[(cc) * 2][aoff + fm * 512];                  \
    _Pragma("unroll")                                                          \
    for (int i = 0; i < 4; i++)                                                \
      bf[i] = *(const f16x8*)&sm[(cc) * 2 + 1][boff + i * 512];                \
  } while (0)

#define MFMA32() do {                                                          \
    __builtin_amdgcn_s_setprio(1);                                             \
    _Pragma("unroll")                                                          \
    for (int fm = 0; fm < 8; fm++) { _Pragma("unroll")                         \
      for (int i = 0; i < 4; i++)                                              \
        acc[fm][i] = MFMA(af[fm], bf[i], acc[fm][i]);                          \
    }                                                                          \
    __builtin_amdgcn_s_setprio(0);                                             \
    SBAR();                                                                    \
  } while (0)

  const int nsteps = K >> 5;
  // prologue: stage step 0 into buf 0
  STAGE(0, 0, 0);
  STAGE(0, 1, 0);
  VMCNT(0);
  BARRIER();

  for (int t = 0; t < nsteps - 1; ++t) {
    const int c = t & 1;
    const int kt1 = (t + 1) << 5;
    LOADS(c);                // ds_read step-t fragments
    STAGE(c ^ 1, 0, kt1);    // issue step-t+1 loads (drained pre-barrier)
    STAGE(c ^ 1, 1, kt1);
    LGKM0();                 // own ds_reads complete
    MFMA32();
    VMCNT(0);                // t+1 loads landed (hidden under MFMA cluster)
    BARRIER();               // all waves: reads of buf c done, t+1 visible
  }
  {  // last step: no staging
    LOADS((nsteps - 1) & 1);
    LGKM0();
    MFMA32();
  }

#pragma unroll
  for (int fm = 0; fm < 8; fm++)
#pragma unroll
    for (int fn = 0; fn < 4; fn++)
#pragma unroll
      for (int q = 0; q < 4; q++) {
        size_t grow = (size_t)bx * 256 + wm * 128 + fm * 16 + kg * 4 + q;
        int gcol = by * 256 + wn * 64 + fn * 16 + lr;
        if (OUTF32)
          ((float*)Cg)[z * zC + grow * ldc + gcol] = acc[fm][fn][q];
        else
          ((f16*)Cg)[z * zC + grow * ldc + gcol] = (f16)acc[fm][fn][q];
      }
#undef STAGE
#undef LOADS
#undef MFMA32
}

// ---------------------------------------------------------------------------
// Row softmax: SC row (2048 f32) -> Pb row (2048 f16)
// ---------------------------------------------------------------------------
__global__ __launch_bounds__(256)
void softmax_rows(const float* __restrict__ SC, f16* __restrict__ Pb) {
  const float* r = SC + (size_t)blockIdx.x * 2048;
  f16* po = Pb + (size_t)blockIdx.x * 2048;
  const int tid = threadIdx.x;
  f32x4 a = *(const f32x4*)(r + tid * 8);
  f32x4 b = *(const f32x4*)(r + tid * 8 + 4);
  float x[8] = {a[0], a[1], a[2], a[3], b[0], b[1], b[2], b[3]};
#pragma unroll
  for (int i = 0; i < 8; i++) x[i] = fminf(fmaxf(x[i], -1e30f), 1e30f);
  float m = x[0];
#pragma unroll
  for (int i = 1; i < 8; i++) m = fmaxf(m, x[i]);
#pragma unroll
  for (int off = 32; off; off >>= 1) m = fmaxf(m, __shfl_xor(m, off));
  __shared__ float rmax[4], rsum[4];
  const int w = tid >> 6, lane = tid & 63;
  if (!lane) rmax[w] = m;
  __syncthreads();
  m = fmaxf(fmaxf(rmax[0], rmax[1]), fmaxf(rmax[2], rmax[3]));
  float e[8], s = 0.f;
#pragma unroll
  for (int i = 0; i < 8; i++) {
    e[i] = __expf(x[i] - m);
    s += e[i];
  }
#pragma unroll
  for (int off = 32; off; off >>= 1) s += __shfl_xor(s, off);
  if (!lane) rsum[w] = s;
  __syncthreads();
  s = rsum[0] + rsum[1] + rsum[2] + rsum[3];
  float inv = 1.0f / s;
  f16x8 p;
#pragma unroll
  for (int i = 0; i < 8; i++) p[i] = (f16)(e[i] * inv);
  *(f16x8*)(po + tid * 8) = p;
}

// ---------------------------------------------------------------------------
extern "C" void kernel_launch(void* const* d_in, const int* in_sizes, int n_in,
                              void* d_out, int out_size, void* d_ws, size_t ws_size,
                              hipStream_t stream) {
  const float* S1 = (const float*)d_in[0];
  const float* S2 = (const float*)d_in[1];
  const float* W1 = (const float*)d_in[2];
  const float* W2 = (const float*)d_in[3];
  float* out = (float*)d_out;
  const int B = 8, N = 2048, H = 1024;
  const size_t NH = (size_t)N * H;  // 2M elems
  const size_t NN = (size_t)N * N;  // 4M elems
  const size_t WN = (size_t)H * H;  // 1M elems

  char* ws = (char*)d_ws;
  f16* W1h = (f16*)ws;
  f16* W2h = W1h + WN;
  size_t fixed = 2 * WN * sizeof(f16);  // 4 MB
  size_t perb = 5 * NH * sizeof(f16) + NN * sizeof(float) + NN * sizeof(f16);

  int bc = 1;
  const int cands[4] = {8, 4, 2, 1};
  for (int ci = 0; ci < 4; ci++) {
    if (fixed + (size_t)cands[ci] * perb <= ws_size) { bc = cands[ci]; break; }
  }
  f16* Ah = (f16*)(ws + fixed);       // S1 chunk f16
  f16* Bh = Ah + (size_t)bc * NH;     // S2 chunk f16
  f16* At = Bh + (size_t)bc * NH;     // S1 chunk transposed f16 [z][1024][2048]
  f16* Bt = At + (size_t)bc * NH;     // S2 chunk transposed
  f16* Kh = Bt + (size_t)bc * NH;     // proj output
  float* SC = (float*)(Kh + (size_t)bc * NH);
  f16* Pb = (f16*)(SC + (size_t)bc * NN);

  {
    int n4 = (int)(WN / 4);
    tof16_kernel<<<dim3((n4 + 255) / 256), 256, 0, stream>>>(W1, W1h, n4);
    tof16_kernel<<<dim3((n4 + 255) / 256), 256, 0, stream>>>(W2, W2h, n4);
  }

  for (int c0 = 0; c0 < B; c0 += bc) {
    prep_f16_kernel<<<dim3(N / 64, H / 64, bc), 256, 0, stream>>>(
        S1 + (size_t)c0 * NH, Ah, At);
    prep_f16_kernel<<<dim3(N / 64, H / 64, bc), 256, 0, stream>>>(
        S2 + (size_t)c0 * NH, Bh, Bt);

    for (int path = 0; path < 2; path++) {
      const f16* Qh = path ? Bh : Ah;  // query side (f16)
      const f16* Xh = path ? Ah : Bh;  // proj input (f16)
      const f16* Vt = path ? At : Bt;  // V transposed [z][1024][2048]
      const f16* Wh = path ? W2h : W1h;
      float* Op = out + (size_t)path * B * NH + (size_t)c0 * NH;

      // Kh = Xh @ W^T : M = bc*2048, N = 1024, K = 1024  (ZB=1, gx=bc*8)
      gemm256<0><<<dim3(bc * 32), 512, 0, stream>>>(
          Xh, 0, Wh, 0, Kh, 0, H, H, H, H, 1, bc * 8);
      // SC = Qh @ Kh^T per batch: 2048x2048, K = 1024  (ZB=bc, gx=8)
      gemm256<1><<<dim3(bc * 64), 512, 0, stream>>>(
          Qh, NH, Kh, NH, SC, NN, H, H, N, H, bc, 8);
      // softmax rows -> Pb f16
      softmax_rows<<<dim3(bc * N), 256, 0, stream>>>(SC, Pb);
      // O = Pb @ Vt^T : per batch 2048x1024, K = 2048  (ZB=bc, gx=8)
      gemm256<1><<<dim3(bc * 32), 512, 0, stream>>>(
          Pb, NN, Vt, NH, Op, NH, N, N, H, N, bc, 8);
    }
  }
}

// Round 10
// 560.899 us; speedup vs baseline: 7.4116x; 7.4116x over previous
//
#include <hip/hip_runtime.h>

typedef _Float16 f16;
typedef _Float16 f16x4 __attribute__((ext_vector_type(4)));
typedef _Float16 f16x8 __attribute__((ext_vector_type(8)));
typedef float    f32x4 __attribute__((ext_vector_type(4)));

#define MFMA(a,b,c) __builtin_amdgcn_mfma_f32_16x16x32_f16(a,b,c,0,0,0)
#define SBAR() __builtin_amdgcn_sched_barrier(0)
#define BARRIER() do { SBAR(); __builtin_amdgcn_s_barrier(); SBAR(); } while (0)
#define VMCNT(n) do { SBAR(); asm volatile("s_waitcnt vmcnt(" #n ")" ::: "memory"); SBAR(); } while (0)
#define LGKM0() do { asm volatile("s_waitcnt lgkmcnt(0)" ::: "memory"); SBAR(); } while (0)

__device__ __forceinline__ void gload_lds16(const f16* g, f16* l) {
  __builtin_amdgcn_global_load_lds(
      (const __attribute__((address_space(1))) unsigned int*)g,
      (__attribute__((address_space(3))) unsigned int*)l, 16, 0, 0);
}

// ---------------------------------------------------------------------------
// f32 -> f16 elementwise convert (weights only)
// ---------------------------------------------------------------------------
__global__ __launch_bounds__(256)
void tof16_kernel(const float* __restrict__ x, f16* __restrict__ y, int n4) {
  int i = blockIdx.x * 256 + threadIdx.x;
  if (i >= n4) return;
  f32x4 v = ((const f32x4*)x)[i];
  f16x4 h;
#pragma unroll
  for (int j = 0; j < 4; j++) h[j] = (f16)v[j];
  ((f16x4*)y)[i] = h;
}

// ---------------------------------------------------------------------------
// Fused convert + transpose: in f32 [z][2048][1024]
//   -> rm f16 [z][2048][1024] (row-major)  and  tr f16 [z][1024][2048]
// ---------------------------------------------------------------------------
__global__ __launch_bounds__(256)
void prep_f16_kernel(const float* __restrict__ in, f16* __restrict__ rm,
                     f16* __restrict__ tr) {
  __shared__ f16 t[64][68];
  const int tid = threadIdx.x;
  const size_t z = blockIdx.z;
  const int n0 = blockIdx.x * 64, h0 = blockIdx.y * 64;
  const int rr = tid >> 4, cc = (tid & 15) * 4;
#pragma unroll
  for (int p = 0; p < 4; p++) {
    int n = rr + p * 16;
    f32x4 v = *(const f32x4*)(in + ((size_t)z * 2048 + n0 + n) * 1024 + h0 + cc);
    f16x4 h;
#pragma unroll
    for (int j = 0; j < 4; j++) h[j] = (f16)v[j];
    *(f16x4*)&t[n][cc] = h;
    *(f16x4*)(rm + ((size_t)z * 2048 + n0 + n) * 1024 + h0 + cc) = h;
  }
  __syncthreads();
#pragma unroll
  for (int p = 0; p < 4; p++) {
    int h = rr + p * 16;
    f16x4 o;
#pragma unroll
    for (int j = 0; j < 4; j++) o[j] = t[cc + j][h];
    *(f16x4*)(tr + ((size_t)z * 1024 + h0 + h) * 2048 + n0 + cc) = o;
  }
}

// ---------------------------------------------------------------------------
// 128x256-tile GEMM, 256 threads (4 waves, per-wave 64x128), 72 KB LDS ->
// 2 blocks/CU (two independent barrier domains fill each other's stalls).
//   C = A(f16,[M][K],lda) * B(f16,[N][K],ldb)^T
// BK=32 steps, THREE buffers (24 KB each: A 128x32, B 256x32), lead = 2
// steps, 6 gload_lds calls/step, steady-state counted vmcnt(6) (waits only
// step-t+1's unit; t+2's 6 stay in flight). One barrier per K-step.
// Block mapping (batch-per-XCD): u = id % ZB, k = id / ZB; bx = k % gx,
// by = k / gx.
// ---------------------------------------------------------------------------
template <int OUTF32>
__global__ __launch_bounds__(256, 2)
void gemm128(const f16* __restrict__ Ag, size_t zA,
             const f16* __restrict__ Bg, size_t zB,
             void* __restrict__ Cg, size_t zC,
             int lda, int ldb, int ldc, int K, int ZB, int gx) {
  __shared__ f16 sm[3][12288];  // [buf][A:128*32 | B:256*32], 72 KB
  const int tid = threadIdx.x;
  const int id = blockIdx.x;
  const size_t z = id % ZB;
  const int k = id / ZB;
  const int bx = k % gx, by = k / gx;
  const f16* A = Ag + z * zA + (size_t)bx * 128 * lda;
  const f16* B = Bg + z * zB + (size_t)by * 256 * ldb;

  const int lane = tid & 63, w = tid >> 6;
  const int wm = w >> 1, wn = w & 1;
  const int lr = lane & 15, kg = lane >> 4;
  const int sx = (kg ^ ((lr >> 1) & 3)) << 3;  // swizzled chunk for reads
  const int aoff = wm * 2048 + lr * 32 + sx;            // A: row*32
  const int boff = 4096 + wn * 4096 + lr * 32 + sx;     // B after A's 4096 halfs
  const int colx = (((tid & 3) ^ ((tid >> 3) & 3)) << 3);  // pre-swizzled src col
  const int srow = tid >> 2;   // 4 lanes/row, 64 rows per call
  const int wls = w * 512;     // wave-uniform LDS base (halfs) per call

  f32x4 acc[4][8] = {};
  f16x8 af[4], bf[8];

  // stage one K-step into buffer cc: A = 2 calls, B = 4 calls (4 KB each)
#define STAGE(cc, ktc) do {                                                    \
    _Pragma("unroll")                                                          \
    for (int p = 0; p < 2; p++)                                                \
      gload_lds16(A + (size_t)(p * 64 + srow) * lda + (ktc) + colx,            \
                  &sm[cc][p * 2048 + wls]);                                    \
    _Pragma("unroll")                                                          \
    for (int p = 0; p < 4; p++)                                                \
      gload_lds16(B + (size_t)(p * 64 + srow) * ldb + (ktc) + colx,            \
                  &sm[cc][4096 + p * 2048 + wls]);                             \
  } while (0)

#define LOADS(cc) do { _Pragma("unroll")                                       \
    for (int fm = 0; fm < 4; fm++)                                             \
      af[fm] = *(const f16x8*)&sm[cc][aoff + fm * 512];                        \
    _Pragma("unroll")                                                          \
    for (int fn = 0; fn < 8; fn++)                                             \
      bf[fn] = *(const f16x8*)&sm[cc][boff + fn * 512];                        \
  } while (0)

#define MFMA32() do {                                                          \
    __builtin_amdgcn_s_setprio(1);                                             \
    _Pragma("unroll")                                                          \
    for (int fm = 0; fm < 4; fm++) { _Pragma("unroll")                         \
      for (int fn = 0; fn < 8; fn++)                                           \
        acc[fm][fn] = MFMA(af[fm], bf[fn], acc[fm][fn]);                       \
    }                                                                          \
    __builtin_amdgcn_s_setprio(0);                                             \
    SBAR();                                                                    \
  } while (0)

  const int nsteps = K >> 5;
  // prologue: stage steps 0,1 into bufs 0,1; wait step 0 (6 newest in flight)
  STAGE(0, 0);
  STAGE(1, 32);
  VMCNT(6);
  BARRIER();

  for (int t = 0; t < nsteps - 2; ++t) {
    const int c = t % 3;
    LOADS(c);                       // ds_read step-t fragments
    STAGE((t + 2) % 3, (t + 2) << 5);  // issue step-t+2 loads
    LGKM0();                        // own ds_reads complete
    MFMA32();
    VMCNT(6);                       // step-t+1 units landed; t+2 in flight
    BARRIER();
  }
  {  // step nsteps-2: no staging; drain everything for the last step
    LOADS((nsteps - 2) % 3);
    LGKM0();
    MFMA32();
    VMCNT(0);
    BARRIER();
  }
  {  // last step
    LOADS((nsteps - 1) % 3);
    LGKM0();
    MFMA32();
  }

#pragma unroll
  for (int fm = 0; fm < 4; fm++)
#pragma unroll
    for (int fn = 0; fn < 8; fn++)
#pragma unroll
      for (int q = 0; q < 4; q++) {
        size_t grow = (size_t)bx * 128 + wm * 64 + fm * 16 + kg * 4 + q;
        int gcol = by * 256 + wn * 128 + fn * 16 + lr;
        if (OUTF32)
          ((float*)Cg)[z * zC + grow * ldc + gcol] = acc[fm][fn][q];
        else
          ((f16*)Cg)[z * zC + grow * ldc + gcol] = (f16)acc[fm][fn][q];
      }
#undef STAGE
#undef LOADS
#undef MFMA32
}

// ---------------------------------------------------------------------------
// Row softmax: SC row (2048 f32) -> Pb row (2048 f16)
// ---------------------------------------------------------------------------
__global__ __launch_bounds__(256)
void softmax_rows(const float* __restrict__ SC, f16* __restrict__ Pb) {
  const float* r = SC + (size_t)blockIdx.x * 2048;
  f16* po = Pb + (size_t)blockIdx.x * 2048;
  const int tid = threadIdx.x;
  f32x4 a = *(const f32x4*)(r + tid * 8);
  f32x4 b = *(const f32x4*)(r + tid * 8 + 4);
  float x[8] = {a[0], a[1], a[2], a[3], b[0], b[1], b[2], b[3]};
#pragma unroll
  for (int i = 0; i < 8; i++) x[i] = fminf(fmaxf(x[i], -1e30f), 1e30f);
  float m = x[0];
#pragma unroll
  for (int i = 1; i < 8; i++) m = fmaxf(m, x[i]);
#pragma unroll
  for (int off = 32; off; off >>= 1) m = fmaxf(m, __shfl_xor(m, off));
  __shared__ float rmax[4], rsum[4];
  const int w = tid >> 6, lane = tid & 63;
  if (!lane) rmax[w] = m;
  __syncthreads();
  m = fmaxf(fmaxf(rmax[0], rmax[1]), fmaxf(rmax[2], rmax[3]));
  float e[8], s = 0.f;
#pragma unroll
  for (int i = 0; i < 8; i++) {
    e[i] = __expf(x[i] - m);
    s += e[i];
  }
#pragma unroll
  for (int off = 32; off; off >>= 1) s += __shfl_xor(s, off);
  if (!lane) rsum[w] = s;
  __syncthreads();
  s = rsum[0] + rsum[1] + rsum[2] + rsum[3];
  float inv = 1.0f / s;
  f16x8 p;
#pragma unroll
  for (int i = 0; i < 8; i++) p[i] = (f16)(e[i] * inv);
  *(f16x8*)(po + tid * 8) = p;
}

// ---------------------------------------------------------------------------
extern "C" void kernel_launch(void* const* d_in, const int* in_sizes, int n_in,
                              void* d_out, int out_size, void* d_ws, size_t ws_size,
                              hipStream_t stream) {
  const float* S1 = (const float*)d_in[0];
  const float* S2 = (const float*)d_in[1];
  const float* W1 = (const float*)d_in[2];
  const float* W2 = (const float*)d_in[3];
  float* out = (float*)d_out;
  const int B = 8, N = 2048, H = 1024;
  const size_t NH = (size_t)N * H;  // 2M elems
  const size_t NN = (size_t)N * N;  // 4M elems
  const size_t WN = (size_t)H * H;  // 1M elems

  char* ws = (char*)d_ws;
  f16* W1h = (f16*)ws;
  f16* W2h = W1h + WN;
  size_t fixed = 2 * WN * sizeof(f16);  // 4 MB
  size_t perb = 5 * NH * sizeof(f16) + NN * sizeof(float) + NN * sizeof(f16);

  int bc = 1;
  const int cands[4] = {8, 4, 2, 1};
  for (int ci = 0; ci < 4; ci++) {
    if (fixed + (size_t)cands[ci] * perb <= ws_size) { bc = cands[ci]; break; }
  }
  f16* Ah = (f16*)(ws + fixed);       // S1 chunk f16
  f16* Bh = Ah + (size_t)bc * NH;     // S2 chunk f16
  f16* At = Bh + (size_t)bc * NH;     // S1 chunk transposed f16 [z][1024][2048]
  f16* Bt = At + (size_t)bc * NH;     // S2 chunk transposed
  f16* Kh = Bt + (size_t)bc * NH;     // proj output
  float* SC = (float*)(Kh + (size_t)bc * NH);
  f16* Pb = (f16*)(SC + (size_t)bc * NN);

  {
    int n4 = (int)(WN / 4);
    tof16_kernel<<<dim3((n4 + 255) / 256), 256, 0, stream>>>(W1, W1h, n4);
    tof16_kernel<<<dim3((n4 + 255) / 256), 256, 0, stream>>>(W2, W2h, n4);
  }

  for (int c0 = 0; c0 < B; c0 += bc) {
    prep_f16_kernel<<<dim3(N / 64, H / 64, bc), 256, 0, stream>>>(
        S1 + (size_t)c0 * NH, Ah, At);
    prep_f16_kernel<<<dim3(N / 64, H / 64, bc), 256, 0, stream>>>(
        S2 + (size_t)c0 * NH, Bh, Bt);

    for (int path = 0; path < 2; path++) {
      const f16* Qh = path ? Bh : Ah;  // query side (f16)
      const f16* Xh = path ? Ah : Bh;  // proj input (f16)
      const f16* Vt = path ? At : Bt;  // V transposed [z][1024][2048]
      const f16* Wh = path ? W2h : W1h;
      float* Op = out + (size_t)path * B * NH + (size_t)c0 * NH;

      // Kh = Xh @ W^T : M = bc*2048 (bx), N = 1024 (by=4), K = 1024
      gemm128<0><<<dim3(bc * 64), 256, 0, stream>>>(
          Xh, 0, Wh, 0, Kh, 0, H, H, H, H, 1, bc * 16);
      // SC = Qh @ Kh^T per batch: 2048x2048 (bx=16, by=8), K = 1024
      gemm128<1><<<dim3(bc * 128), 256, 0, stream>>>(
          Qh, NH, Kh, NH, SC, NN, H, H, N, H, bc, 16);
      // softmax rows -> Pb f16
      softmax_rows<<<dim3(bc * N), 256, 0, stream>>>(SC, Pb);
      // O = Pb @ Vt^T per batch: 2048x1024 (bx=16, by=4), K = 2048
      gemm128<1><<<dim3(bc * 64), 256, 0, stream>>>(
          Pb, NN, Vt, NH, Op, NH, N, N, H, N, bc, 16);
    }
  }
}

// Round 11
// 544.861 us; speedup vs baseline: 7.6298x; 1.0294x over previous
//
#include <hip/hip_runtime.h>

typedef _Float16 f16;
typedef _Float16 f16x4 __attribute__((ext_vector_type(4)));
typedef _Float16 f16x8 __attribute__((ext_vector_type(8)));
typedef float    f32x4 __attribute__((ext_vector_type(4)));

#define MFMA(a,b,c) __builtin_amdgcn_mfma_f32_16x16x32_f16(a,b,c,0,0,0)
#define SBAR() __builtin_amdgcn_sched_barrier(0)
#define BARRIER() do { SBAR(); __builtin_amdgcn_s_barrier(); SBAR(); } while (0)
#define VMCNT(n) do { SBAR(); asm volatile("s_waitcnt vmcnt(" #n ")" ::: "memory"); SBAR(); } while (0)

__device__ __forceinline__ void gload_lds16(const f16* g, f16* l) {
  __builtin_amdgcn_global_load_lds(
      (const __attribute__((address_space(1))) unsigned int*)g,
      (__attribute__((address_space(3))) unsigned int*)l, 16, 0, 0);
}

// ---------------------------------------------------------------------------
// f32 -> f16 elementwise convert (weights only)
// ---------------------------------------------------------------------------
__global__ __launch_bounds__(256)
void tof16_kernel(const float* __restrict__ x, f16* __restrict__ y, int n4) {
  int i = blockIdx.x * 256 + threadIdx.x;
  if (i >= n4) return;
  f32x4 v = ((const f32x4*)x)[i];
  f16x4 h;
#pragma unroll
  for (int j = 0; j < 4; j++) h[j] = (f16)v[j];
  ((f16x4*)y)[i] = h;
}

// ---------------------------------------------------------------------------
// Fused convert + transpose: in f32 [z][2048][1024]
//   -> rm f16 [z][2048][1024] (row-major)  and  tr f16 [z][1024][2048]
// ---------------------------------------------------------------------------
__global__ __launch_bounds__(256)
void prep_f16_kernel(const float* __restrict__ in, f16* __restrict__ rm,
                     f16* __restrict__ tr) {
  __shared__ f16 t[64][68];
  const int tid = threadIdx.x;
  const size_t z = blockIdx.z;
  const int n0 = blockIdx.x * 64, h0 = blockIdx.y * 64;
  const int rr = tid >> 4, cc = (tid & 15) * 4;
#pragma unroll
  for (int p = 0; p < 4; p++) {
    int n = rr + p * 16;
    f32x4 v = *(const f32x4*)(in + ((size_t)z * 2048 + n0 + n) * 1024 + h0 + cc);
    f16x4 h;
#pragma unroll
    for (int j = 0; j < 4; j++) h[j] = (f16)v[j];
    *(f16x4*)&t[n][cc] = h;
    *(f16x4*)(rm + ((size_t)z * 2048 + n0 + n) * 1024 + h0 + cc) = h;
  }
  __syncthreads();
#pragma unroll
  for (int p = 0; p < 4; p++) {
    int h = rr + p * 16;
    f16x4 o;
#pragma unroll
    for (int j = 0; j < 4; j++) o[j] = t[cc + j][h];
    *(f16x4*)(tr + ((size_t)z * 1024 + h0 + h) * 2048 + n0 + cc) = o;
  }
}

// ---------------------------------------------------------------------------
// 256x256-tile GEMM, compiler-scheduled interleave:
//   C = A(f16,[M][K],lda) * B(f16,[N][K],ldb)^T
// Per K-tile (BK=64): {issue 8 gloads for t+1 | SBAR | 16 ds_read
// (af kk0 + bf kk0 + bf kk1) | 32 MFMA kk0 (compiler hoists the 8 af-kk1
// ds_reads into this cluster via counted lgkmcnt) | 32 MFMA kk1 |
// vmcnt(0) | barrier}.  ONE barrier per K-tile; no manual lgkmcnt/setprio
// fences -- the serialized {LDS window | MFMA window} alternation of r4-r10
// is dissolved by letting the scheduler overlap the two pipes.
// Block mapping (batch-per-XCD): u = id % ZB, k = id / ZB; bx = k % gx,
// by = k / gx.
// ---------------------------------------------------------------------------
template <int OUTF32>
__global__ __launch_bounds__(512, 2)
void gemm256(const f16* __restrict__ Ag, size_t zA,
             const f16* __restrict__ Bg, size_t zB,
             void* __restrict__ Cg, size_t zC,
             int lda, int ldb, int ldc, int K, int ZB, int gx) {
  __shared__ f16 sm[8][8192];  // [c*4 + mat*2 + kk][256*32], 128 KB
  const int tid = threadIdx.x;
  const int id = blockIdx.x;
  const size_t z = id % ZB;
  const int k = id / ZB;
  const int bx = k % gx, by = k / gx;
  const f16* A = Ag + z * zA + (size_t)bx * 256 * lda;
  const f16* B = Bg + z * zB + (size_t)by * 256 * ldb;

  const int lane = tid & 63, w = tid >> 6;
  const int wm = w >> 2, wn = w & 3;
  const int lr = lane & 15, kg = lane >> 4;
  const int sx = (kg ^ ((lr >> 1) & 3)) << 3;      // swizzled chunk for reads
  const int aoff = wm * 4096 + lr * 32 + sx;
  const int boff = wn * 2048 + lr * 32 + sx;
  const int colx = (((tid & 3) ^ ((tid >> 3) & 3)) << 3);  // pre-swizzled src col
  const int srow = tid >> 2;
  const int wls = w * 512;  // wave-uniform LDS base (halfs) per issue

  f32x4 acc[8][4] = {};
  f16x8 af[8], bf0[4], bf1[4];

#define STAGE(cc, mat, kkv, ktc) do {                                          \
    const f16* gs = ((mat) ? B : A) + (size_t)srow * ((mat) ? ldb : lda) +     \
                    (ktc) + (kkv) * 32 + colx;                                 \
    f16* ls = &sm[(cc) * 4 + (mat) * 2 + (kkv)][wls];                          \
    gload_lds16(gs, ls);                                                       \
    gload_lds16(gs + (size_t)128 * ((mat) ? ldb : lda), ls + 4096);            \
  } while (0)

#define LOAD_A(cc, kkv) do { _Pragma("unroll")                                 \
    for (int fm = 0; fm < 8; fm++)                                             \
      af[fm] = *(const f16x8*)&sm[(cc) * 4 + (kkv)][aoff + fm * 512];          \
  } while (0)

#define LOAD_B4(cc, kkv, arr) do { _Pragma("unroll")                           \
    for (int i = 0; i < 4; i++)                                                \
      arr[i] = *(const f16x8*)&sm[(cc) * 4 + 2 + (kkv)][boff + i * 512];       \
  } while (0)

#define MFMA32(arr) do { _Pragma("unroll")                                     \
    for (int fm = 0; fm < 8; fm++) { _Pragma("unroll")                         \
      for (int i = 0; i < 4; i++)                                              \
        acc[fm][i] = MFMA(af[fm], arr[i], acc[fm][i]);                         \
    }                                                                          \
  } while (0)

  const int nt = K >> 6;
  // prologue: stage tile 0 (units A0,B0,A1,B1) into buf 0
  STAGE(0, 0, 0, 0);
  STAGE(0, 1, 0, 0);
  STAGE(0, 0, 1, 0);
  STAGE(0, 1, 1, 0);
  VMCNT(0);
  BARRIER();

  for (int t = 0; t < nt - 1; ++t) {
    const int c = t & 1;
    const int kt1 = (t + 1) << 6;
    // issue next tile's 8 gloads first (drained by end-of-tile vmcnt)
    STAGE(c ^ 1, 0, 0, kt1);
    STAGE(c ^ 1, 1, 0, kt1);
    STAGE(c ^ 1, 0, 1, kt1);
    STAGE(c ^ 1, 1, 1, kt1);
    SBAR();  // pin gloads above the compute; below is compiler-scheduled
    LOAD_A(c, 0);
    LOAD_B4(c, 0, bf0);
    LOAD_B4(c, 1, bf1);
    MFMA32(bf0);
    LOAD_A(c, 1);
    MFMA32(bf1);
    VMCNT(0);   // t+1's units landed (issued one full MFMA-span ago)
    BARRIER();
  }
  {  // last tile: no staging, no trailing barrier
    const int c = (nt - 1) & 1;
    LOAD_A(c, 0);
    LOAD_B4(c, 0, bf0);
    LOAD_B4(c, 1, bf1);
    MFMA32(bf0);
    LOAD_A(c, 1);
    MFMA32(bf1);
  }

#pragma unroll
  for (int fm = 0; fm < 8; fm++)
#pragma unroll
    for (int fn = 0; fn < 4; fn++)
#pragma unroll
      for (int q = 0; q < 4; q++) {
        size_t grow = (size_t)bx * 256 + wm * 128 + fm * 16 + kg * 4 + q;
        int gcol = by * 256 + wn * 64 + fn * 16 + lr;
        if (OUTF32)
          ((float*)Cg)[z * zC + grow * ldc + gcol] = acc[fm][fn][q];
        else
          ((f16*)Cg)[z * zC + grow * ldc + gcol] = (f16)acc[fm][fn][q];
      }
#undef STAGE
#undef LOAD_A
#undef LOAD_B4
#undef MFMA32
}

// ---------------------------------------------------------------------------
// Row softmax: SC row (2048 f32) -> Pb row (2048 f16)
// ---------------------------------------------------------------------------
__global__ __launch_bounds__(256)
void softmax_rows(const float* __restrict__ SC, f16* __restrict__ Pb) {
  const float* r = SC + (size_t)blockIdx.x * 2048;
  f16* po = Pb + (size_t)blockIdx.x * 2048;
  const int tid = threadIdx.x;
  f32x4 a = *(const f32x4*)(r + tid * 8);
  f32x4 b = *(const f32x4*)(r + tid * 8 + 4);
  float x[8] = {a[0], a[1], a[2], a[3], b[0], b[1], b[2], b[3]};
#pragma unroll
  for (int i = 0; i < 8; i++) x[i] = fminf(fmaxf(x[i], -1e30f), 1e30f);
  float m = x[0];
#pragma unroll
  for (int i = 1; i < 8; i++) m = fmaxf(m, x[i]);
#pragma unroll
  for (int off = 32; off; off >>= 1) m = fmaxf(m, __shfl_xor(m, off));
  __shared__ float rmax[4], rsum[4];
  const int w = tid >> 6, lane = tid & 63;
  if (!lane) rmax[w] = m;
  __syncthreads();
  m = fmaxf(fmaxf(rmax[0], rmax[1]), fmaxf(rmax[2], rmax[3]));
  float e[8], s = 0.f;
#pragma unroll
  for (int i = 0; i < 8; i++) {
    e[i] = __expf(x[i] - m);
    s += e[i];
  }
#pragma unroll
  for (int off = 32; off; off >>= 1) s += __shfl_xor(s, off);
  if (!lane) rsum[w] = s;
  __syncthreads();
  s = rsum[0] + rsum[1] + rsum[2] + rsum[3];
  float inv = 1.0f / s;
  f16x8 p;
#pragma unroll
  for (int i = 0; i < 8; i++) p[i] = (f16)(e[i] * inv);
  *(f16x8*)(po + tid * 8) = p;
}

// ---------------------------------------------------------------------------
extern "C" void kernel_launch(void* const* d_in, const int* in_sizes, int n_in,
                              void* d_out, int out_size, void* d_ws, size_t ws_size,
                              hipStream_t stream) {
  const float* S1 = (const float*)d_in[0];
  const float* S2 = (const float*)d_in[1];
  const float* W1 = (const float*)d_in[2];
  const float* W2 = (const float*)d_in[3];
  float* out = (float*)d_out;
  const int B = 8, N = 2048, H = 1024;
  const size_t NH = (size_t)N * H;  // 2M elems
  const size_t NN = (size_t)N * N;  // 4M elems
  const size_t WN = (size_t)H * H;  // 1M elems

  char* ws = (char*)d_ws;
  f16* W1h = (f16*)ws;
  f16* W2h = W1h + WN;
  size_t fixed = 2 * WN * sizeof(f16);  // 4 MB
  size_t perb = 5 * NH * sizeof(f16) + NN * sizeof(float) + NN * sizeof(f16);

  int bc = 1;
  const int cands[4] = {8, 4, 2, 1};
  for (int ci = 0; ci < 4; ci++) {
    if (fixed + (size_t)cands[ci] * perb <= ws_size) { bc = cands[ci]; break; }
  }
  f16* Ah = (f16*)(ws + fixed);       // S1 chunk f16
  f16* Bh = Ah + (size_t)bc * NH;     // S2 chunk f16
  f16* At = Bh + (size_t)bc * NH;     // S1 chunk transposed f16 [z][1024][2048]
  f16* Bt = At + (size_t)bc * NH;     // S2 chunk transposed
  f16* Kh = Bt + (size_t)bc * NH;     // proj output
  float* SC = (float*)(Kh + (size_t)bc * NH);
  f16* Pb = (f16*)(SC + (size_t)bc * NN);

  {
    int n4 = (int)(WN / 4);
    tof16_kernel<<<dim3((n4 + 255) / 256), 256, 0, stream>>>(W1, W1h, n4);
    tof16_kernel<<<dim3((n4 + 255) / 256), 256, 0, stream>>>(W2, W2h, n4);
  }

  for (int c0 = 0; c0 < B; c0 += bc) {
    prep_f16_kernel<<<dim3(N / 64, H / 64, bc), 256, 0, stream>>>(
        S1 + (size_t)c0 * NH, Ah, At);
    prep_f16_kernel<<<dim3(N / 64, H / 64, bc), 256, 0, stream>>>(
        S2 + (size_t)c0 * NH, Bh, Bt);

    for (int path = 0; path < 2; path++) {
      const f16* Qh = path ? Bh : Ah;  // query side (f16)
      const f16* Xh = path ? Ah : Bh;  // proj input (f16)
      const f16* Vt = path ? At : Bt;  // V transposed [z][1024][2048]
      const f16* Wh = path ? W2h : W1h;
      float* Op = out + (size_t)path * B * NH + (size_t)c0 * NH;

      // Kh = Xh @ W^T : M = bc*2048, N = 1024, K = 1024  (ZB=1, gx=bc*8)
      gemm256<0><<<dim3(bc * 32), 512, 0, stream>>>(
          Xh, 0, Wh, 0, Kh, 0, H, H, H, H, 1, bc * 8);
      // SC = Qh @ Kh^T per batch: 2048x2048, K = 1024  (ZB=bc, gx=8)
      gemm256<1><<<dim3(bc * 64), 512, 0, stream>>>(
          Qh, NH, Kh, NH, SC, NN, H, H, N, H, bc, 8);
      // softmax rows -> Pb f16
      softmax_rows<<<dim3(bc * N), 256, 0, stream>>>(SC, Pb);
      // O = Pb @ Vt^T : per batch 2048x1024, K = 2048  (ZB=bc, gx=8)
      gemm256<1><<<dim3(bc * 32), 512, 0, stream>>>(
          Pb, NN, Vt, NH, Op, NH, N, N, H, N, bc, 8);
    }
  }
}